// Round 1
// baseline (802.992 us; speedup 1.0000x reference)
//
#include <hip/hip_runtime.h>

// BinTokenizer: tokens = clip(searchsorted(linspace(0,1,257), clip(x,eps,1-eps), 'right')-1, 0, 255)
// thresholds[i] = i/256 exactly in fp32; x*256 is exact (power-of-2 scale), so
// token == (int)(clip(x, 1e-6f, 1.0f-1e-6f) * 256.0f). No binary search needed.
// Memory-bound: 512 MiB in + 512 MiB out -> ~170 us floor at 6.3 TB/s.

__device__ __forceinline__ int tokenize1(float x) {
    // clip into (low+eps, high-eps)
    x = fminf(fmaxf(x, 1e-6f), 1.0f - 1e-6f);
    // floor(x*256): x>0 so truncation == floor; x <= 0.999999f so result <= 255
    return (int)(x * 256.0f);
}

__global__ __launch_bounds__(256) void BinTokenizer_90812788507001_kernel(
        const float4* __restrict__ in, int4* __restrict__ out, int n4) {
    int i = blockIdx.x * blockDim.x + threadIdx.x;
    if (i < n4) {
        float4 v = in[i];
        int4 t;
        t.x = tokenize1(v.x);
        t.y = tokenize1(v.y);
        t.z = tokenize1(v.z);
        t.w = tokenize1(v.w);
        out[i] = t;
    }
}

extern "C" void kernel_launch(void* const* d_in, const int* in_sizes, int n_in,
                              void* d_out, int out_size, void* d_ws, size_t ws_size,
                              hipStream_t stream) {
    const float4* in = (const float4*)d_in[0];   // inputs, 64*4096*512 fp32
    // d_in[1] = thresholds (uniform linspace) -- math folded into the kernel
    int4* out = (int4*)d_out;                    // int32 tokens
    int n = in_sizes[0];
    int n4 = n >> 2;                             // 134217728 % 4 == 0
    int block = 256;
    int grid = (n4 + block - 1) / block;
    BinTokenizer_90812788507001_kernel<<<grid, block, 0, stream>>>(in, out, n4);
}